// Round 10
// baseline (983.907 us; speedup 1.0000x reference)
//
#include <hip/hip_runtime.h>
#include <hip/hip_bf16.h>
#include <math.h>

#define D_MODEL 2048
#define SEQ     2048
#define BATCH   2
#define NTOK    (BATCH*SEQ)      // 4096
#define NHEAD   16
#define HDIM    128
#define FF      8192

typedef float  f32x4  __attribute__((ext_vector_type(4)));
typedef __bf16 bf16x8 __attribute__((ext_vector_type(8)));

__device__ __forceinline__ unsigned short f2bfbits(float f) {
    unsigned u = __builtin_bit_cast(unsigned, f);
    return (unsigned short)((u + 0x7fffu + ((u >> 16) & 1u)) >> 16);
}
__device__ __forceinline__ __bf16 f2bf(float f) {
    unsigned short h = f2bfbits(f);
    return __builtin_bit_cast(__bf16, h);
}

__device__ __forceinline__ void gld_lds16(const void* g, void* l) {
    __builtin_amdgcn_global_load_lds(
        (const __attribute__((address_space(1))) unsigned int*)g,
        (__attribute__((address_space(3))) unsigned int*)l, 16, 0, 0);
}

#define BAR()      __builtin_amdgcn_s_barrier()
#define LGKM(N)    asm volatile("s_waitcnt lgkmcnt(" #N ")" ::: "memory")
#define VMCNT(N)   asm volatile("s_waitcnt vmcnt(" #N ")" ::: "memory")
#define SCHEDB()   __builtin_amdgcn_sched_barrier(0)

// ---------------- fused f32 -> bf16 convert for tok + all 6 weights -------------
__global__ __launch_bounds__(256) void cvt_all(
        const float* __restrict__ tok, const float* __restrict__ wq,
        const float* __restrict__ wk,  const float* __restrict__ wv,
        const float* __restrict__ wo,  const float* __restrict__ w1,
        const float* __restrict__ w2,
        __bf16* __restrict__ tokb, __bf16* __restrict__ wqb,
        __bf16* __restrict__ wkb,  __bf16* __restrict__ wvb,
        __bf16* __restrict__ wob,  __bf16* __restrict__ w1b,
        __bf16* __restrict__ w2b) {
    const size_t M4 = 4u * 1024 * 1024;
    size_t i = (size_t)blockIdx.x * 1024 + (size_t)threadIdx.x * 4;
    const float* src; __bf16* dst; size_t off;
    if      (i < 2*M4)  { src = tok; dst = tokb; off = i; }
    else if (i < 3*M4)  { src = wq;  dst = wqb;  off = i - 2*M4; }
    else if (i < 4*M4)  { src = wk;  dst = wkb;  off = i - 3*M4; }
    else if (i < 5*M4)  { src = wv;  dst = wvb;  off = i - 4*M4; }
    else if (i < 6*M4)  { src = wo;  dst = wob;  off = i - 5*M4; }
    else if (i < 10*M4) { src = w1;  dst = w1b;  off = i - 6*M4; }
    else                { src = w2;  dst = w2b;  off = i - 10*M4; }
    float4 v = *(const float4*)(src + off);
    ushort4 o;
    o.x = f2bfbits(v.x); o.y = f2bfbits(v.y);
    o.z = f2bfbits(v.z); o.w = f2bfbits(v.w);
    *(ushort4*)((unsigned short*)dst + off) = o;
}

// ---------------- split-K reduce: out = p0 + p1 + resid (f32) ----------------
__global__ __launch_bounds__(256) void add_reduce(
        const float* __restrict__ p0, const float* __restrict__ p1,
        const float* __restrict__ resid, float* __restrict__ out) {
    int i = blockIdx.x * 256 + threadIdx.x;
    float4 a = ((const float4*)p0)[i];
    float4 b = ((const float4*)p1)[i];
    float4 r = ((const float4*)resid)[i];
    float4 o;
    o.x = a.x + b.x + r.x; o.y = a.y + b.y + r.y;
    o.z = a.z + b.z + r.z; o.w = a.w + b.w + r.w;
    ((float4*)out)[i] = o;
}

// ---------------- LayerNorm: f32 in -> bf16 out, one block per row ----------------
__global__ __launch_bounds__(256) void ln_bf16(
        const float* __restrict__ x, const float* __restrict__ w,
        const float* __restrict__ b, __bf16* __restrict__ out) {
    const int row = blockIdx.x;
    const int tid = threadIdx.x;
    const float* xr = x + (size_t)row * D_MODEL;
    float4 v0 = *(const float4*)(xr + tid * 8);
    float4 v1 = *(const float4*)(xr + tid * 8 + 4);
    float va[8] = {v0.x, v0.y, v0.z, v0.w, v1.x, v1.y, v1.z, v1.w};
    float s = 0.f, ss = 0.f;
#pragma unroll
    for (int j = 0; j < 8; ++j) { s += va[j]; ss += va[j] * va[j]; }
#pragma unroll
    for (int m = 32; m; m >>= 1) { s += __shfl_xor(s, m, 64); ss += __shfl_xor(ss, m, 64); }
    __shared__ float red[8];
    const int wid = tid >> 6;
    if ((tid & 63) == 0) { red[wid * 2] = s; red[wid * 2 + 1] = ss; }
    __syncthreads();
    s  = red[0] + red[2] + red[4] + red[6];
    ss = red[1] + red[3] + red[5] + red[7];
    const float mu   = s * (1.0f / D_MODEL);
    const float var  = ss * (1.0f / D_MODEL) - mu * mu;
    const float rstd = rsqrtf(var + 1e-5f);
    const int c = tid * 8;
    ushort4 o0, o1;
    unsigned short ob[8];
#pragma unroll
    for (int j = 0; j < 8; ++j)
        ob[j] = f2bfbits((va[j] - mu) * rstd * w[c + j] + b[c + j]);
    o0.x = ob[0]; o0.y = ob[1]; o0.z = ob[2]; o0.w = ob[3];
    o1.x = ob[4]; o1.y = ob[5]; o1.z = ob[6]; o1.w = ob[7];
    ushort4* op = (ushort4*)(out + (size_t)row * D_MODEL + c);
    op[0] = o0; op[1] = o1;
}

// ================== GEMM core (device) ==================
// C[M,N] = A[M,K] @ B[N,K]^T, 512 threads = 8 waves.
//
// GEO=0: 256x256 tile, waves 2Mx4N own 128x64, acc[8][4]. PIPELINED-LGKM
//   8-phase schedule (2 K-tiles a=buf0/b=buf1 per iteration): ds_reads are
//   issued ONE PHASE AHEAD and waited with COUNTED lgkmcnt, so each phase's
//   LDS drain overlaps the previous phase's MFMA (m196's fine interleave;
//   lgkm analog of T4's counted vmcnt).
//   Reads/wave/tile: R1={af0,bq0}[12 b128], R2={bq1}[4], R3={af1}[8].
//     prologue: issue R1(a)
//     ph1: issue R2(a); bar; lgkm(4)  [R1 landed, R2 flying]; M1=af0*bq0; bar
//     ph2: issue R3(a); bar; lgkm(8)  [R2 landed, R3 flying]; M2=af0*bq1; bar
//     ph3:            bar; lgkm(0)  [R3 landed];            M3=af1*bq0; vmcnt; bar
//     ph4: issue R1(b);bar;            M4=af1*bq1 (reg-only); bar
//     ph5-8: mirror for tile b; ph8 issues R1(a+2).
//   Staging (1 half-tile = 2 gld/thread per phase):
//     ph1-2: A(b)->buf1.A   [last reads R3(b_prev) drained prev-ph7 lgkm(0)]
//     ph3-4: B(a+2)->buf0.B [R1(a) drained ph1, R2(a) drained ph2]
//     ph5-6: A(a+2)->buf0.A [R3(a) drained ph3]
//     ph7-8: B(b+2)->buf1.B [R1(b) drained ph5, R2(b) drained ph6]
//   Gates (vmcnt BEFORE barrier; 2 gld/phase): entry invariant 4 outstanding
//   (B(b)); ph3-end outstanding 10 -> VMCNT(2) drains B(b)+A(b) before ph4's
//   R1(b) read issue; ph7-end outstanding 10 -> VMCNT(2) drains B(a+2)+A(a+2)
//   before ph8's R1(a+2). Last iteration (pf=0): VMCNT(0) at ph3.
//   Every region restage follows a barrier that follows all waves' lgkm-drain
//   of that region's last reads => no gld-write vs ds_read race.
// GEO=1: 128x256 tile, waves own 64x64, acc[4][4]; 1 phase/K-tile, 3 buffers
//        (144KB), 2-tile-deep prefetch, counted vmcnt(6).
// Swizzle both-sides (rule #21): 16B-chunk col X ^= (r&7)<<4 -> 2-way = free.
// EPI: 0 bf16 | 1 GELU bf16 | 2 f32+resid | 3 bf16 transposed [b,h,hd,s] | 4 f32 partial

template <int EPI, int MM>
__device__ __forceinline__ void gemm_epi(
        f32x4 (*acc)[4], int BMsz, int WMsz,
        int bm, int bn, int wm, int wn, int lhi, int l16,
        int M, int N, int slice,
        __bf16* __restrict__ Cb, float* __restrict__ Cf,
        const float* __restrict__ resid) {
#pragma unroll
    for (int m = 0; m < MM; ++m) {
        const int row = bm * BMsz + wm * WMsz + m * 16 + lhi * 4;
#pragma unroll
        for (int n = 0; n < 4; ++n) {
            const int col = bn * 256 + wn * 64 + n * 16 + l16;
            if (EPI == 3) {
                const int h = col >> 7, hd = col & 127;
                const size_t obase =
                    ((((size_t)(row >> 11) * NHEAD + h) * HDIM + hd) << 11) + (row & 2047);
                ushort4 o;
                o.x = f2bfbits(acc[m][n][0]); o.y = f2bfbits(acc[m][n][1]);
                o.z = f2bfbits(acc[m][n][2]); o.w = f2bfbits(acc[m][n][3]);
                *(ushort4*)((unsigned short*)Cb + obase) = o;
            } else {
#pragma unroll
                for (int r = 0; r < 4; ++r) {
                    float v = acc[m][n][r];
                    size_t off = (size_t)(row + r) * N + col;
                    if (EPI == 0) {
                        Cb[off] = f2bf(v);
                    } else if (EPI == 1) {
                        Cb[off] = f2bf(0.5f * v * (1.0f + erff(v * 0.70710678118654752f)));
                    } else if (EPI == 2) {
                        Cf[off] = v + resid[off];
                    } else {  // EPI == 4
                        Cf[(size_t)slice * M * N + off] = v;
                    }
                }
            }
        }
    }
}

template <int EPI, int SPLITK, int GEO>
__device__ __forceinline__ void gemm_core(
        const __bf16* __restrict__ A, const __bf16* __restrict__ Bm,
        __bf16* __restrict__ Cb, float* __restrict__ Cf,
        const float* __restrict__ resid, int M, int N, int K,
        int bm, int bn, int slice, char* smem) {
    const int tid = threadIdx.x;
    const int wid = tid >> 6, lane = tid & 63;
    const int l16 = lane & 15, lhi = lane >> 4;
    const int wm = wid >> 2, wn = wid & 3;
    const int tps = (K >> 6) / SPLITK;
    const int t0 = slice * tps, t1 = t0 + tps;

    // stage 128 rows x 64 cols (16KB): inverse-swizzled source, linear LDS dest
    auto stage128 = [&](char* dst, const __bf16* G, int kt, int rowOff) {
#pragma unroll
        for (int j = 0; j < 2; ++j) {
            int idx = j * 512 + tid;            // 0..1023 chunks
            int r = idx >> 3;                   // 0..127
            int Xc = (idx & 7) << 4;
            int Xs = Xc ^ ((r & 7) << 4);
            gld_lds16((const char*)(G + ((size_t)(rowOff + r) * K + kt * 64)) + Xs,
                      dst + idx * 16);
        }
    };

    if constexpr (GEO == 0) {
        const __bf16* Ag = A  + (size_t)bm * 256 * K;
        const __bf16* Bg = Bm + (size_t)bn * 256 * K;
        f32x4 acc[8][4] = {};
        bf16x8 af0[4][2], af1[4][2], bq0[2][2], bq1[2][2];
        const char *Ab_, *Bb_;
        auto ldA = [&](bf16x8 (&dst)[4][2], int qm) {
#pragma unroll
            for (int i = 0; i < 4; ++i)
#pragma unroll
                for (int ks = 0; ks < 2; ++ks) {
                    int r = wm * 128 + (qm * 4 + i) * 16 + l16;
                    int X = ks * 64 + lhi * 16;
                    dst[i][ks] = *(const bf16x8*)(Ab_ + r * 128 + (X ^ ((r & 7) << 4)));
                }
        };
        auto ldB = [&](bf16x8 (&dst)[2][2], int qn) {
#pragma unroll
            for (int j = 0; j < 2; ++j)
#pragma unroll
                for (int ks = 0; ks < 2; ++ks) {
                    int r = wn * 64 + (qn * 2 + j) * 16 + l16;
                    int X = ks * 64 + lhi * 16;
                    dst[j][ks] = *(const bf16x8*)(Bb_ + r * 128 + (X ^ ((r & 7) << 4)));
                }
        };
        auto mfmaQ = [&](bf16x8 (&a)[4][2], bf16x8 (&b)[2][2], int mo, int no) {
            __builtin_amdgcn_s_setprio(1);
#pragma unroll
            for (int i = 0; i < 4; ++i)
#pragma unroll
                for (int j = 0; j < 2; ++j)
#pragma unroll
                    for (int ks = 0; ks < 2; ++ks)
                        acc[mo + i][no + j] = __builtin_amdgcn_mfma_f32_16x16x32_bf16(
                            a[i][ks], b[j][ks], acc[mo + i][no + j], 0, 0, 0);
            __builtin_amdgcn_s_setprio(0);
        };
        // regions: buf0.A @0, buf0.B @32K, buf1.A @64K, buf1.B @96K
        // t0 even for every caller (tps even), so (t&1) == buffer slot.
        auto stA = [&](int t, int half) {
            stage128(smem + ((t & 1) ? 65536 : 0) + half * 16384, Ag, t, half * 128);
        };
        auto stB = [&](int t, int half) {
            stage128(smem + ((t & 1) ? 98304 : 32768) + half * 16384, Bg, t, half * 128);
        };

        // prologue: A(t0), B(t0), B(t0+1); land A(t0),B(t0) (B(t0+1) flying = 4)
        stA(t0, 0); stA(t0, 1);
        stB(t0, 0); stB(t0, 1);
        stB(t0 + 1, 0); stB(t0 + 1, 1);
        VMCNT(4);
        BAR();
        Ab_ = smem; Bb_ = smem + 32768;
        ldA(af0, 0); ldB(bq0, 0);          // R1(t0) in flight

        for (int ta = t0; ta < t1; ta += 2) {
            const int tb = ta + 1;
            const bool pf = (ta + 2 < t1);
            Ab_ = smem; Bb_ = smem + 32768;          // tile a = buf0
            // ph1: issue R2(a); stage A(b)h0; M1 while R2 drains
            ldB(bq1, 1);
            stA(tb, 0);
            BAR(); LGKM(4); SCHEDB();
            mfmaQ(af0, bq0, 0, 0);
            BAR();
            // ph2: issue R3(a); stage A(b)h1; M2 while R3 drains
            ldA(af1, 1);
            stA(tb, 1);
            BAR(); LGKM(8); SCHEDB();
            mfmaQ(af0, bq1, 0, 2);
            BAR();
            // ph3: stage B(a+2)h0; M3; gate A(b),B(b) landed
            if (pf) stB(ta + 2, 0);
            BAR(); LGKM(0); SCHEDB();
            mfmaQ(af1, bq0, 4, 0);
            if (pf) { VMCNT(2); } else { VMCNT(0); }
            BAR();
            // ph4: issue R1(b) from buf1; stage B(a+2)h1; M4(a) register-only
            Ab_ = smem + 65536; Bb_ = smem + 98304;  // tile b = buf1
            ldA(af0, 0); ldB(bq0, 0);
            if (pf) stB(ta + 2, 1);
            BAR(); SCHEDB();
            mfmaQ(af1, bq1, 4, 2);
            BAR();
            // ph5: issue R2(b); stage A(a+2)h0; M1(b) while R1(b) tail drains
            ldB(bq1, 1);
            if (pf) stA(ta + 2, 0);
            BAR(); LGKM(4); SCHEDB();
            mfmaQ(af0, bq0, 0, 0);
            BAR();
            // ph6: issue R3(b); stage A(a+2)h1; M2(b)
            ldA(af1, 1);
            if (pf) stA(ta + 2, 1);
            BAR(); LGKM(8); SCHEDB();
            mfmaQ(af0, bq1, 0, 2);
            BAR();
            // ph7: stage B(b+2)h0; M3(b); gate A(a+2),B(a+2) landed
            if (pf) stB(tb + 2, 0);
            BAR(); LGKM(0); SCHEDB();
            mfmaQ(af1, bq0, 4, 0);
            if (pf) { VMCNT(2); } else { VMCNT(0); }
            BAR();
            // ph8: issue R1(a+2) from buf0; stage B(b+2)h1; M4(b) register-only
            if (pf) {
                Ab_ = smem; Bb_ = smem + 32768;
                ldA(af0, 0); ldB(bq0, 0);
                stB(tb + 2, 1);
            }
            BAR(); SCHEDB();
            mfmaQ(af1, bq1, 4, 2);
            BAR();
        }
        gemm_epi<EPI, 8>(acc, 256, 128, bm, bn, wm, wn, lhi, l16,
                         M, N, slice, Cb, Cf, resid);
    } else {
        // GEO1: 128x256 tile, 3 buffers (48KB each), 2-tile-deep, counted vmcnt(6)
        const __bf16* Ag = A  + (size_t)bm * 128 * K;
        const __bf16* Bg = Bm + (size_t)bn * 256 * K;
        f32x4 acc[4][4] = {};
        auto stageT = [&](int t, int c) {
            char* base = smem + c * 49152;
            stage128(base,         Ag, t, 0);      // A: 128x64 = 16KB
            stage128(base + 16384, Bg, t, 0);      // B: 256x64 = 32KB
            stage128(base + 32768, Bg, t, 128);
        };
        stageT(t0, 0);
        if (t0 + 1 < t1) {
            stageT(t0 + 1, 1);
            VMCNT(6);
        } else {
            VMCNT(0);
        }
        BAR();

        for (int t = t0; t < t1; ++t) {
            const int c = (t - t0) % 3;
            if (t + 2 < t1) stageT(t + 2, (c + 2) % 3);
            const char* Ab_ = smem + c * 49152;
            const char* Bb_ = Ab_ + 16384;
            bf16x8 af[4][2], bq[4][2];
#pragma unroll
            for (int i = 0; i < 4; ++i)
#pragma unroll
                for (int ks = 0; ks < 2; ++ks) {
                    int r = wm * 64 + i * 16 + l16;
                    int X = ks * 64 + lhi * 16;
                    af[i][ks] = *(const bf16x8*)(Ab_ + r * 128 + (X ^ ((r & 7) << 4)));
                }
#pragma unroll
            for (int j = 0; j < 4; ++j)
#pragma unroll
                for (int ks = 0; ks < 2; ++ks) {
                    int r = wn * 64 + j * 16 + l16;
                    int X = ks * 64 + lhi * 16;
                    bq[j][ks] = *(const bf16x8*)(Bb_ + r * 128 + (X ^ ((r & 7) << 4)));
                }
            LGKM(0); SCHEDB();
            __builtin_amdgcn_s_setprio(1);
#pragma unroll
            for (int i = 0; i < 4; ++i)
#pragma unroll
                for (int j = 0; j < 4; ++j)
#pragma unroll
                    for (int ks = 0; ks < 2; ++ks)
                        acc[i][j] = __builtin_amdgcn_mfma_f32_16x16x32_bf16(
                            af[i][ks], bq[j][ks], acc[i][j], 0, 0, 0);
            __builtin_amdgcn_s_setprio(0);
            if (t + 2 < t1) {
                VMCNT(6);
                BAR();
            } else if (t + 1 < t1) {
                VMCNT(0);
                BAR();
            }
        }
        gemm_epi<EPI, 4>(acc, 128, 64, bm, bn, wm, wn, lhi, l16,
                         M, N, slice, Cb, Cf, resid);
    }
}

// MAP: 0 = generic XCD round-robin swizzle; 1 = bn-stripes of 4 per XCD (FFN1);
// 2 = bm-stripes of 4 per XCD (O-proj).
template <int EPI, int SPLITK, int GEO, int MAP>
__global__ __launch_bounds__(512, 2) void gemm_k(
        const __bf16* __restrict__ A, const __bf16* __restrict__ Bm,
        __bf16* __restrict__ Cb, float* __restrict__ Cf,
        const float* __restrict__ resid, int M, int N, int K) {
    __shared__ __align__(16) char smem[GEO ? 147456 : 131072];
    int bm, bn, slice = 0;
    if (MAP == 0) {
        int id = blockIdx.x;
        const int cpx = gridDim.x >> 3;
        id = (id & 7) * cpx + (id >> 3);
        const int nbn = N >> 8;
        if (SPLITK == 2) {
            const int nblk = (M >> (GEO ? 7 : 8)) * nbn;
            slice = id / nblk;
            id -= slice * nblk;
        }
        bm = id / nbn; bn = id % nbn;
    } else if (MAP == 1) {
        const int x = blockIdx.x & 7, j = blockIdx.x >> 3;
        bn = (x << 2) | (j & 3); bm = j >> 2;
    } else {
        const int x = blockIdx.x & 7, j = blockIdx.x >> 3;
        bm = (x << 2) | (j & 3); bn = j >> 2;
    }
    gemm_core<EPI, SPLITK, GEO>(A, Bm, Cb, Cf, resid, M, N, K, bm, bn, slice, smem);
}

// Grouped QK + V projection: 512 blocks. Per XCD x: j<32 -> QK tile (256x256),
// j>=32 -> V tile (128x256, EPI=3 transposed out).
__global__ __launch_bounds__(512, 2) void gemm_qkv(
        const __bf16* __restrict__ hn, const __bf16* __restrict__ wqk,
        __bf16* __restrict__ QKb, const __bf16* __restrict__ tokb,
        const __bf16* __restrict__ wv, __bf16* __restrict__ Vtg) {
    __shared__ __align__(16) char smem[147456];
    const int x = blockIdx.x & 7, j = blockIdx.x >> 3;   // x = XCD, j = 0..63
    if (j < 32) {
        const int bm = ((x >> 1) << 2) | (j & 3);        // 0..15
        const int bn = ((x & 1) << 3) | (j >> 2);        // 0..15
        gemm_core<0, 1, 0>(hn, wqk, QKb, nullptr, nullptr,
                           NTOK, 2 * D_MODEL, D_MODEL, bm, bn, 0, smem);
    } else {
        const int jv = j - 32;
        const int bm = ((x >> 1) << 3) | (jv & 7);       // 0..31
        const int bn = ((x & 1) << 2) | (jv >> 3);       // 0..7
        gemm_core<3, 1, 1>(tokb, wv, Vtg, nullptr, nullptr,
                           NTOK, D_MODEL, D_MODEL, bm, bn, 0, smem);
    }
}

// ---------------- Causal flash attention (8 waves, QBLK=128, pipelined) ----------
#define LDQK 4096
__global__ __launch_bounds__(512) void attn_causal(
        const __bf16* __restrict__ Q, const __bf16* __restrict__ K,
        const __bf16* __restrict__ Vt, __bf16* __restrict__ O) {
    const int qt = gridDim.x - 1 - blockIdx.x;
    const int h = blockIdx.y, bb = blockIdx.z;
    const int tid = threadIdx.x, wid = tid >> 6, lane = tid & 63;
    const int l16 = lane & 15, lhi = lane >> 4;
    __shared__ __align__(16) __bf16 Ks[2][64 * 128];
    __shared__ __align__(16) __bf16 Vs[128 * 64];
    __shared__ __align__(16) __bf16 Pl[8][16 * 72];

    const size_t qkbase = ((size_t)bb * SEQ) * LDQK + (size_t)h * HDIM;
    const size_t obase  = ((size_t)bb * SEQ) * D_MODEL + (size_t)h * HDIM;
    const size_t vtbase = (((size_t)bb * NHEAD + h) * HDIM) << 11;
    const int q0 = qt * 128 + wid * 16;

    bf16x8 qf[4];
#pragma unroll
    for (int ks = 0; ks < 4; ++ks)
        qf[ks] = *(const bf16x8*)(Q + qkbase + (size_t)(q0 + l16) * LDQK + ks * 32 + lhi * 8);

    auto stageK = [&](int kt, int buf) {
#pragma unroll
        for (int j = 0; j < 2; ++j) {
            int idx = j * 512 + tid;
            int row = idx >> 4, c8 = idx & 15;
            int c8s = c8 ^ (row & 7);
            gld_lds16(K + qkbase + (size_t)(kt * 64 + row) * LDQK + c8s * 8,
                      &Ks[buf][0] + idx * 8);
        }
    };
    auto stageV = [&](int kt) {
#pragma unroll
        for (int j = 0; j < 2; ++j) {
            int idx = j * 512 + tid;
            int row = idx >> 3, c8 = idx & 7;
            int c8s = c8 ^ (row & 7);
            gld_lds16(Vt + vtbase + (size_t)row * SEQ + kt * 64 + c8s * 8, Vs + idx * 8);
        }
    };

    f32x4 accO[8] = {};
    float m_run[4], l_run[4];
#pragma unroll
    for (int r = 0; r < 4; ++r) { m_run[r] = -1e30f; l_run[r] = 0.f; }

    const float scale2 = 0.08838834764831845f * 1.4426950408889634f;
    const int NKT = (qt + 1) * 2;

    stageK(0, 0);
    VMCNT(0);
    BAR();
    SCHEDB();

    for (int kt = 0; kt < NKT; ++kt) {
        const int cb = kt & 1;
        const bool pf = (kt + 1 < NKT);
        stageV(kt);
        if (pf) stageK(kt + 1, cb ^ 1);

        f32x4 s[4] = {};
        __builtin_amdgcn_s_setprio(1);
#pragma unroll
        for (int nb = 0; nb < 4; ++nb) {
            const int tok = nb * 16 + l16;
#pragma unroll
            for (int ks = 0; ks < 4; ++ks) {
                int co = (ks * 64 + lhi * 16) ^ ((tok & 7) << 4);
                bf16x8 kf = *(const bf16x8*)((const char*)&Ks[cb][0] + tok * 256 + co);
                s[nb] = __builtin_amdgcn_mfma_f32_16x16x32_bf16(qf[ks], kf, s[nb], 0, 0, 0);
            }
        }
        __builtin_amdgcn_s_setprio(0);

        if (((kt + 1) << 6) > q0) {
#pragma unroll
            for (int nb = 0; nb < 4; ++nb)
#pragma unroll
                for (int r = 0; r < 4; ++r) {
                    float sv = s[nb][r] * scale2;
                    if ((kt * 64 + nb * 16 + l16) > (q0 + lhi * 4 + r)) sv = -1e30f;
                    s[nb][r] = sv;
                }
        } else {
#pragma unroll
            for (int nb = 0; nb < 4; ++nb)
#pragma unroll
                for (int r = 0; r < 4; ++r) s[nb][r] *= scale2;
        }

        float alpha[4];
#pragma unroll
        for (int r = 0; r < 4; ++r) {
            float mx = fmaxf(fmaxf(s[0][r], s[1][r]), fmaxf(s[2][r], s[3][r]));
#pragma unroll
            for (int m = 8; m; m >>= 1) mx = fmaxf(mx, __shfl_xor(mx, m, 64));
            float mnew = fmaxf(m_run[r], mx);
            alpha[r] = exp2f(m_run[r] - mnew);
            float rs = 0.f;
#pragma unroll
            for (int nb = 0; nb < 4; ++nb) {
                float p = exp2f(s[nb][r] - mnew);
                s[nb][r] = p;
                rs += p;
            }
#pragma unroll
            for (int m = 8; m; m >>= 1) rs += __shfl_xor(rs, m, 64);
            l_run[r] = l_run[r] * alpha[r] + rs;
            m_run[r] = mnew;
        }
#pragma unroll
        for (int d8 = 0; d8 < 8; ++d8)
#pragma unroll
            for (int r = 0; r < 4; ++r) accO[d8][r] *= alpha[r];
#pragma unroll
        for (int nb = 0; nb < 4; ++nb)
#pragma unroll
            for (int r = 0; r < 4; ++r)
                Pl[wid][(lhi * 4 + r) * 72 + nb * 16 + l16] = f2bf(s[nb][r]);

        if (pf) { VMCNT(2); } else { VMCNT(0); }
        BAR();
        SCHEDB();

        __builtin_amdgcn_s_setprio(1);
#pragma unroll
        for (int ks2 = 0; ks2 < 2; ++ks2) {
            bf16x8 pa = *(const bf16x8*)(&Pl[wid][l16 * 72 + ks2 * 32 + lhi * 8]);
#pragma unroll
            for (int d8 = 0; d8 < 8; ++d8) {
                const int d = d8 * 16 + l16;
                const int co = ((ks2 * 4 + lhi) ^ (d & 7)) << 4;
                bf16x8 vf = *(const bf16x8*)((const char*)Vs + d * 128 + co);
                accO[d8] = __builtin_amdgcn_mfma_f32_16x16x32_bf16(pa, vf, accO[d8], 0, 0, 0);
            }
        }
        __builtin_amdgcn_s_setprio(0);

        VMCNT(0);
        BAR();
        SCHEDB();
    }

#pragma unroll
    for (int d8 = 0; d8 < 8; ++d8)
#pragma unroll
        for (int r = 0; r < 4; ++r) {
            float o = accO[d8][r] / l_run[r];
            O[obase + (size_t)(q0 + lhi * 4 + r) * D_MODEL + d8 * 16 + l16] = f2bf(o);
        }
}

// ---------------- host launcher ----------------
extern "C" void kernel_launch(void* const* d_in, const int* in_sizes, int n_in,
                              void* d_out, int out_size, void* d_ws, size_t ws_size,
                              hipStream_t stream) {
    const float* x    = (const float*)d_in[0];
    const float* tok  = (const float*)d_in[1];
    const float* Wq   = (const float*)d_in[2];
    const float* Wk   = (const float*)d_in[3];
    const float* Wv   = (const float*)d_in[4];
    const float* Wo   = (const float*)d_in[5];
    const float* W1   = (const float*)d_in[6];
    const float* W2   = (const float*)d_in[7];
    const float* ln1w = (const float*)d_in[8];
    const float* ln1b = (const float*)d_in[9];
    const float* ln2w = (const float*)d_in[10];
    const float* ln2b = (const float*)d_in[11];
    float* out = (float*)d_out;

    char* ws = (char*)d_ws;
    size_t off = 0;
    auto alloc = [&](size_t bytes) { void* p = ws + off; off += bytes; return p; };
    __bf16* tokb  = (__bf16*)alloc((size_t)NTOK * D_MODEL * 2);       //   0-16 MB
    __bf16* hnorm = (__bf16*)alloc((size_t)NTOK * D_MODEL * 2);       //  16-32
    __bf16* wqb   = (__bf16*)alloc((size_t)D_MODEL * D_MODEL * 2);    //  32-40 (wq|wk adjacent)
    __bf16* wkb   = (__bf16*)alloc((size_t)D_MODEL * D_MODEL * 2);    //  40-48
    __bf16* wvb   = (__bf16*)alloc((size_t)D_MODEL * D_MODEL * 2);    //  48-56
    __bf16* wob   = (__bf16*)alloc((size_t)D_MODEL * D_MODEL * 2);    //  56-64
    __bf16* w1b   = (__bf16*)alloc((size_t)FF * D_MODEL * 2);         //  64-96
    __bf16* w2b   = (__bf16*)alloc((size_t)D_MODEL * FF * 2);         //  96-128
    __bf16* QKb   = (__bf16*)alloc((size_t)NTOK * 2 * D_MODEL * 2);   // 128-160
    __bf16* Vtg   = (__bf16*)alloc((size_t)NTOK * D_MODEL * 2);       // 160-176
    __bf16* Ab    = (__bf16*)alloc((size_t)NTOK * D_MODEL * 2);       // 176-192
    float*  x2    = (float*)alloc((size_t)NTOK * D_MODEL * 4);        // 192-224 f32
    __bf16* gb    = QKb;              // FFN intermediate aliases QKb.. (dead post O-proj)
    float*  p0    = (float*)(ws);     // W2 split-K partials: 0-32MB / 32-64MB
    float*  p1    = p0 + (size_t)NTOK * D_MODEL;

    cvt_all<<<56 * 1024, 256, 0, stream>>>(tok, Wq, Wk, Wv, Wo, W1, W2,
                                           tokb, wqb, wkb, wvb, wob, w1b, w2b);

    ln_bf16<<<NTOK, 256, 0, stream>>>(x, ln1w, ln1b, hnorm);

    // grouped QK (256 tiles) + V (256 small tiles) = 512 blocks, 2 full rounds
    gemm_qkv<<<512, 512, 0, stream>>>(hnorm, wqb, QKb, tokb, wvb, Vtg);

    attn_causal<<<dim3(SEQ / 128, NHEAD, BATCH), 512, 0, stream>>>(QKb, QKb + D_MODEL, Vtg, Ab);

    // O-proj: GEO1 (128x256) -> 256 blocks, full GPU; MAP=2 bm-stripes per XCD
    gemm_k<2, 1, 1, 2><<<256, 512, 0, stream>>>(Ab, wob, nullptr, x2, x,
                                                NTOK, D_MODEL, D_MODEL);

    ln_bf16<<<NTOK, 256, 0, stream>>>(x2, ln2w, ln2b, hnorm);

    // FFN1: MAP=1 bn-stripes of 4 per XCD (A-panel resident, B 4MB resident)
    gemm_k<1, 1, 0, 1><<<512, 512, 0, stream>>>(hnorm, w1b, gb, nullptr, nullptr,
                                                NTOK, FF, D_MODEL);
    // W2 split-K=2: 256 blocks, f32 partials + fused reduce+residual
    gemm_k<4, 2, 0, 0><<<256, 512, 0, stream>>>(gb, w2b, nullptr, p0, nullptr,
                                                NTOK, D_MODEL, FF);
    add_reduce<<<(NTOK * D_MODEL) / 1024, 256, 0, stream>>>(p0, p1, x2, out);
}

// Round 11
// 671.984 us; speedup vs baseline: 1.4642x; 1.4642x over previous
//
#include <hip/hip_runtime.h>
#include <hip/hip_bf16.h>
#include <math.h>

#define D_MODEL 2048
#define SEQ     2048
#define BATCH   2
#define NTOK    (BATCH*SEQ)      // 4096
#define NHEAD   16
#define HDIM    128
#define FF      8192

typedef float  f32x4  __attribute__((ext_vector_type(4)));
typedef __bf16 bf16x8 __attribute__((ext_vector_type(8)));

__device__ __forceinline__ unsigned short f2bfbits(float f) {
    unsigned u = __builtin_bit_cast(unsigned, f);
    return (unsigned short)((u + 0x7fffu + ((u >> 16) & 1u)) >> 16);
}
__device__ __forceinline__ __bf16 f2bf(float f) {
    unsigned short h = f2bfbits(f);
    return __builtin_bit_cast(__bf16, h);
}

__device__ __forceinline__ void gld_lds16(const void* g, void* l) {
    __builtin_amdgcn_global_load_lds(
        (const __attribute__((address_space(1))) unsigned int*)g,
        (__attribute__((address_space(3))) unsigned int*)l, 16, 0, 0);
}

#define BAR()      __builtin_amdgcn_s_barrier()
#define LGKM(N)    asm volatile("s_waitcnt lgkmcnt(" #N ")" ::: "memory")
#define VMCNT(N)   asm volatile("s_waitcnt vmcnt(" #N ")" ::: "memory")
#define SCHEDB()   __builtin_amdgcn_sched_barrier(0)

// ---------------- fused f32 -> bf16 convert for tok + all 6 weights -------------
__global__ __launch_bounds__(256) void cvt_all(
        const float* __restrict__ tok, const float* __restrict__ wq,
        const float* __restrict__ wk,  const float* __restrict__ wv,
        const float* __restrict__ wo,  const float* __restrict__ w1,
        const float* __restrict__ w2,
        __bf16* __restrict__ tokb, __bf16* __restrict__ wqb,
        __bf16* __restrict__ wkb,  __bf16* __restrict__ wvb,
        __bf16* __restrict__ wob,  __bf16* __restrict__ w1b,
        __bf16* __restrict__ w2b) {
    const size_t M4 = 4u * 1024 * 1024;
    size_t i = (size_t)blockIdx.x * 1024 + (size_t)threadIdx.x * 4;
    const float* src; __bf16* dst; size_t off;
    if      (i < 2*M4)  { src = tok; dst = tokb; off = i; }
    else if (i < 3*M4)  { src = wq;  dst = wqb;  off = i - 2*M4; }
    else if (i < 4*M4)  { src = wk;  dst = wkb;  off = i - 3*M4; }
    else if (i < 5*M4)  { src = wv;  dst = wvb;  off = i - 4*M4; }
    else if (i < 6*M4)  { src = wo;  dst = wob;  off = i - 5*M4; }
    else if (i < 10*M4) { src = w1;  dst = w1b;  off = i - 6*M4; }
    else                { src = w2;  dst = w2b;  off = i - 10*M4; }
    float4 v = *(const float4*)(src + off);
    ushort4 o;
    o.x = f2bfbits(v.x); o.y = f2bfbits(v.y);
    o.z = f2bfbits(v.z); o.w = f2bfbits(v.w);
    *(ushort4*)((unsigned short*)dst + off) = o;
}

// ---------------- LayerNorm: f32 in -> bf16 out, one block per row ----------------
__global__ __launch_bounds__(256) void ln_bf16(
        const float* __restrict__ x, const float* __restrict__ w,
        const float* __restrict__ b, __bf16* __restrict__ out) {
    const int row = blockIdx.x;
    const int tid = threadIdx.x;
    const float* xr = x + (size_t)row * D_MODEL;
    float4 v0 = *(const float4*)(xr + tid * 8);
    float4 v1 = *(const float4*)(xr + tid * 8 + 4);
    float va[8] = {v0.x, v0.y, v0.z, v0.w, v1.x, v1.y, v1.z, v1.w};
    float s = 0.f, ss = 0.f;
#pragma unroll
    for (int j = 0; j < 8; ++j) { s += va[j]; ss += va[j] * va[j]; }
#pragma unroll
    for (int m = 32; m; m >>= 1) { s += __shfl_xor(s, m, 64); ss += __shfl_xor(ss, m, 64); }
    __shared__ float red[8];
    const int wid = tid >> 6;
    if ((tid & 63) == 0) { red[wid * 2] = s; red[wid * 2 + 1] = ss; }
    __syncthreads();
    s  = red[0] + red[2] + red[4] + red[6];
    ss = red[1] + red[3] + red[5] + red[7];
    const float mu   = s * (1.0f / D_MODEL);
    const float var  = ss * (1.0f / D_MODEL) - mu * mu;
    const float rstd = rsqrtf(var + 1e-5f);
    const int c = tid * 8;
    ushort4 o0, o1;
    unsigned short ob[8];
#pragma unroll
    for (int j = 0; j < 8; ++j)
        ob[j] = f2bfbits((va[j] - mu) * rstd * w[c + j] + b[c + j]);
    o0.x = ob[0]; o0.y = ob[1]; o0.z = ob[2]; o0.w = ob[3];
    o1.x = ob[4]; o1.y = ob[5]; o1.z = ob[6]; o1.w = ob[7];
    ushort4* op = (ushort4*)(out + (size_t)row * D_MODEL + c);
    op[0] = o0; op[1] = o1;
}

// ================== GEMM core (device) ==================
// C[M,N] = A[M,K] @ B[N,K]^T, 512 threads = 8 waves.
// GEO=0 (R7-proven): 256x256 tile, waves 2Mx4N own 128x64, acc[8][4]; 4-phase
//        per K-tile, 2 LDS buffers (128KB); ALL 4 half-tiles of tile t+1 staged
//        at t.P1; vmcnt(0) only at t.P4-end (wait distance ~3 phases).
//        Fragments are read+consumed within each phase (short live ranges — the
//        R10 cross-phase pipelining spilled to scratch and regressed 2x).
// GEO=1: 128x256 tile, waves own 64x64, acc[4][4]; 1 phase/K-tile, 3 buffers
//        (144KB), 2-tile-deep prefetch, counted vmcnt(6), 1 barrier/K-tile.
//        Per-wave per K-tile: 16 ds_read_b128 + 32 MFMA (2x MFMA per lgkm-drain
//        vs GEO0) — used for V-proj/O-proj since R8 (never in top-5), now also
//        FFN1 and W2 (W2: K=8192 -> 128 tiles, no split-K, residual fused).
// Swizzle both-sides (rule #21): 16B-chunk col X ^= (r&7)<<4 -> 2-way = free.
// EPI: 0 bf16 | 1 GELU bf16 | 2 f32+resid | 3 bf16 transposed [b,h,hd,s]

template <int EPI, int MM>
__device__ __forceinline__ void gemm_epi(
        f32x4 (*acc)[4], int BMsz, int WMsz,
        int bm, int bn, int wm, int wn, int lhi, int l16,
        int M, int N, int slice,
        __bf16* __restrict__ Cb, float* __restrict__ Cf,
        const float* __restrict__ resid) {
#pragma unroll
    for (int m = 0; m < MM; ++m) {
        const int row = bm * BMsz + wm * WMsz + m * 16 + lhi * 4;
#pragma unroll
        for (int n = 0; n < 4; ++n) {
            const int col = bn * 256 + wn * 64 + n * 16 + l16;
            if (EPI == 3) {
                const int h = col >> 7, hd = col & 127;
                const size_t obase =
                    ((((size_t)(row >> 11) * NHEAD + h) * HDIM + hd) << 11) + (row & 2047);
                ushort4 o;
                o.x = f2bfbits(acc[m][n][0]); o.y = f2bfbits(acc[m][n][1]);
                o.z = f2bfbits(acc[m][n][2]); o.w = f2bfbits(acc[m][n][3]);
                *(ushort4*)((unsigned short*)Cb + obase) = o;
            } else {
#pragma unroll
                for (int r = 0; r < 4; ++r) {
                    float v = acc[m][n][r];
                    size_t off = (size_t)(row + r) * N + col;
                    if (EPI == 0) {
                        Cb[off] = f2bf(v);
                    } else if (EPI == 1) {
                        Cb[off] = f2bf(0.5f * v * (1.0f + erff(v * 0.70710678118654752f)));
                    } else {  // EPI == 2
                        Cf[off] = v + resid[off];
                    }
                }
            }
        }
    }
}

template <int EPI, int SPLITK, int GEO>
__device__ __forceinline__ void gemm_core(
        const __bf16* __restrict__ A, const __bf16* __restrict__ Bm,
        __bf16* __restrict__ Cb, float* __restrict__ Cf,
        const float* __restrict__ resid, int M, int N, int K,
        int bm, int bn, int slice, char* smem) {
    const int tid = threadIdx.x;
    const int wid = tid >> 6, lane = tid & 63;
    const int l16 = lane & 15, lhi = lane >> 4;
    const int wm = wid >> 2, wn = wid & 3;
    const int tps = (K >> 6) / SPLITK;
    const int t0 = slice * tps, t1 = t0 + tps;

    // stage 128 rows x 64 cols (16KB): inverse-swizzled source, linear LDS dest
    auto stage128 = [&](char* dst, const __bf16* G, int kt, int rowOff) {
#pragma unroll
        for (int j = 0; j < 2; ++j) {
            int idx = j * 512 + tid;            // 0..1023 chunks
            int r = idx >> 3;                   // 0..127
            int Xc = (idx & 7) << 4;
            int Xs = Xc ^ ((r & 7) << 4);
            gld_lds16((const char*)(G + ((size_t)(rowOff + r) * K + kt * 64)) + Xs,
                      dst + idx * 16);
        }
    };

    if constexpr (GEO == 0) {
        const __bf16* Ag = A  + (size_t)bm * 256 * K;
        const __bf16* Bg = Bm + (size_t)bn * 256 * K;
        f32x4 acc[8][4] = {};
        bf16x8 af0[4][2], af1[4][2], bq0[2][2], bq1[2][2];
        const char *Ab_, *Bb_;
        auto ldA = [&](bf16x8 (&dst)[4][2], int qm) {
#pragma unroll
            for (int i = 0; i < 4; ++i)
#pragma unroll
                for (int ks = 0; ks < 2; ++ks) {
                    int r = wm * 128 + (qm * 4 + i) * 16 + l16;
                    int X = ks * 64 + lhi * 16;
                    dst[i][ks] = *(const bf16x8*)(Ab_ + r * 128 + (X ^ ((r & 7) << 4)));
                }
        };
        auto ldB = [&](bf16x8 (&dst)[2][2], int qn) {
#pragma unroll
            for (int j = 0; j < 2; ++j)
#pragma unroll
                for (int ks = 0; ks < 2; ++ks) {
                    int r = wn * 64 + (qn * 2 + j) * 16 + l16;
                    int X = ks * 64 + lhi * 16;
                    dst[j][ks] = *(const bf16x8*)(Bb_ + r * 128 + (X ^ ((r & 7) << 4)));
                }
        };
        auto mfmaQ = [&](bf16x8 (&a)[4][2], bf16x8 (&b)[2][2], int mo, int no) {
            __builtin_amdgcn_s_setprio(1);
#pragma unroll
            for (int i = 0; i < 4; ++i)
#pragma unroll
                for (int j = 0; j < 2; ++j)
#pragma unroll
                    for (int ks = 0; ks < 2; ++ks)
                        acc[mo + i][no + j] = __builtin_amdgcn_mfma_f32_16x16x32_bf16(
                            a[i][ks], b[j][ks], acc[mo + i][no + j], 0, 0, 0);
            __builtin_amdgcn_s_setprio(0);
        };
        auto stageT = [&](int t, int c) {
            char* base = smem + c * 65536;
            stage128(base,         Ag, t, 0);
            stage128(base + 16384, Ag, t, 128);
            stage128(base + 32768, Bg, t, 0);
            stage128(base + 49152, Bg, t, 128);
        };

        stageT(t0, 0);
        VMCNT(0);
        BAR();

        for (int t = t0; t < t1; ++t) {
            const int cur = (t - t0) & 1;
            Ab_ = smem + cur * 65536;
            Bb_ = Ab_ + 32768;
            const bool pf = (t + 1 < t1);
            // P1: issue ALL of tile t+1's staging (max wait distance)
            if (pf) stageT(t + 1, cur ^ 1);
            ldA(af0, 0); ldB(bq0, 0);
            BAR(); LGKM(0); SCHEDB();
            mfmaQ(af0, bq0, 0, 0);
            BAR();
            // P2
            ldB(bq1, 1);
            BAR(); LGKM(0); SCHEDB();
            mfmaQ(af0, bq1, 0, 2);
            BAR();
            // P3
            ldA(af1, 1);
            BAR(); LGKM(0); SCHEDB();
            mfmaQ(af1, bq0, 4, 0);
            BAR();
            // P4: register-only MFMA, then drain (loads issued 3 phases ago)
            mfmaQ(af1, bq1, 4, 2);
            if (pf) VMCNT(0);
            BAR();
        }
        gemm_epi<EPI, 8>(acc, 256, 128, bm, bn, wm, wn, lhi, l16,
                         M, N, slice, Cb, Cf, resid);
    } else {
        // GEO1: 128x256 tile, 3 buffers (48KB each), 2-tile-deep, counted vmcnt(6)
        const __bf16* Ag = A  + (size_t)bm * 128 * K;
        const __bf16* Bg = Bm + (size_t)bn * 256 * K;
        f32x4 acc[4][4] = {};
        auto stageT = [&](int t, int c) {
            char* base = smem + c * 49152;
            stage128(base,         Ag, t, 0);      // A: 128x64 = 16KB
            stage128(base + 16384, Bg, t, 0);      // B: 256x64 = 32KB
            stage128(base + 32768, Bg, t, 128);
        };
        stageT(t0, 0);
        if (t0 + 1 < t1) {
            stageT(t0 + 1, 1);
            VMCNT(6);
        } else {
            VMCNT(0);
        }
        BAR();

        for (int t = t0; t < t1; ++t) {
            const int c = (t - t0) % 3;
            if (t + 2 < t1) stageT(t + 2, (c + 2) % 3);   // buf died at t-1's end barrier
            const char* Ab_ = smem + c * 49152;
            const char* Bb_ = Ab_ + 16384;
            bf16x8 af[4][2], bq[4][2];
#pragma unroll
            for (int i = 0; i < 4; ++i)
#pragma unroll
                for (int ks = 0; ks < 2; ++ks) {
                    int r = wm * 64 + i * 16 + l16;
                    int X = ks * 64 + lhi * 16;
                    af[i][ks] = *(const bf16x8*)(Ab_ + r * 128 + (X ^ ((r & 7) << 4)));
                }
#pragma unroll
            for (int j = 0; j < 4; ++j)
#pragma unroll
                for (int ks = 0; ks < 2; ++ks) {
                    int r = wn * 64 + j * 16 + l16;
                    int X = ks * 64 + lhi * 16;
                    bq[j][ks] = *(const bf16x8*)(Bb_ + r * 128 + (X ^ ((r & 7) << 4)));
                }
            LGKM(0); SCHEDB();
            __builtin_amdgcn_s_setprio(1);
#pragma unroll
            for (int i = 0; i < 4; ++i)
#pragma unroll
                for (int j = 0; j < 4; ++j)
#pragma unroll
                    for (int ks = 0; ks < 2; ++ks)
                        acc[i][j] = __builtin_amdgcn_mfma_f32_16x16x32_bf16(
                            af[i][ks], bq[j][ks], acc[i][j], 0, 0, 0);
            __builtin_amdgcn_s_setprio(0);
            // gate t+1's buffer: counted vmcnt BEFORE barrier
            if (t + 2 < t1) {
                VMCNT(6);
                BAR();
            } else if (t + 1 < t1) {
                VMCNT(0);
                BAR();
            }
        }
        gemm_epi<EPI, 4>(acc, 128, 64, bm, bn, wm, wn, lhi, l16,
                         M, N, slice, Cb, Cf, resid);
    }
}

// MAP: 0 = generic XCD round-robin swizzle; 2 = bm-stripes of 4 per XCD (O-proj).
template <int EPI, int SPLITK, int GEO, int MAP>
__global__ __launch_bounds__(512, 2) void gemm_k(
        const __bf16* __restrict__ A, const __bf16* __restrict__ Bm,
        __bf16* __restrict__ Cb, float* __restrict__ Cf,
        const float* __restrict__ resid, int M, int N, int K) {
    __shared__ __align__(16) char smem[GEO ? 147456 : 131072];
    int bm, bn, slice = 0;
    if (MAP == 0) {
        int id = blockIdx.x;
        const int cpx = gridDim.x >> 3;
        id = (id & 7) * cpx + (id >> 3);
        const int nbn = N >> 8;
        if (SPLITK == 2) {
            const int nblk = (M >> (GEO ? 7 : 8)) * nbn;
            slice = id / nblk;
            id -= slice * nblk;
        }
        bm = id / nbn; bn = id % nbn;
    } else {
        const int x = blockIdx.x & 7, j = blockIdx.x >> 3;
        bm = (x << 2) | (j & 3); bn = j >> 2;
    }
    gemm_core<EPI, SPLITK, GEO>(A, Bm, Cb, Cf, resid, M, N, K, bm, bn, slice, smem);
}

// Grouped QK + V projection: 512 blocks. Per XCD x: j<32 -> QK tile (256x256),
// j>=32 -> V tile (128x256, EPI=3 transposed out).
__global__ __launch_bounds__(512, 2) void gemm_qkv(
        const __bf16* __restrict__ hn, const __bf16* __restrict__ wqk,
        __bf16* __restrict__ QKb, const __bf16* __restrict__ tokb,
        const __bf16* __restrict__ wv, __bf16* __restrict__ Vtg) {
    __shared__ __align__(16) char smem[147456];
    const int x = blockIdx.x & 7, j = blockIdx.x >> 3;   // x = XCD, j = 0..63
    if (j < 32) {
        const int bm = ((x >> 1) << 2) | (j & 3);        // 0..15
        const int bn = ((x & 1) << 3) | (j >> 2);        // 0..15
        gemm_core<0, 1, 0>(hn, wqk, QKb, nullptr, nullptr,
                           NTOK, 2 * D_MODEL, D_MODEL, bm, bn, 0, smem);
    } else {
        const int jv = j - 32;
        const int bm = ((x >> 1) << 3) | (jv & 7);       // 0..31
        const int bn = ((x & 1) << 2) | (jv >> 3);       // 0..7
        gemm_core<3, 1, 1>(tokb, wv, Vtg, nullptr, nullptr,
                           NTOK, D_MODEL, D_MODEL, bm, bn, 0, smem);
    }
}

// ---------------- Causal flash attention (8 waves, QBLK=128, pipelined) ----------
#define LDQK 4096
__global__ __launch_bounds__(512) void attn_causal(
        const __bf16* __restrict__ Q, const __bf16* __restrict__ K,
        const __bf16* __restrict__ Vt, __bf16* __restrict__ O) {
    const int qt = gridDim.x - 1 - blockIdx.x;
    const int h = blockIdx.y, bb = blockIdx.z;
    const int tid = threadIdx.x, wid = tid >> 6, lane = tid & 63;
    const int l16 = lane & 15, lhi = lane >> 4;
    __shared__ __align__(16) __bf16 Ks[2][64 * 128];
    __shared__ __align__(16) __bf16 Vs[128 * 64];
    __shared__ __align__(16) __bf16 Pl[8][16 * 72];

    const size_t qkbase = ((size_t)bb * SEQ) * LDQK + (size_t)h * HDIM;
    const size_t obase  = ((size_t)bb * SEQ) * D_MODEL + (size_t)h * HDIM;
    const size_t vtbase = (((size_t)bb * NHEAD + h) * HDIM) << 11;
    const int q0 = qt * 128 + wid * 16;

    bf16x8 qf[4];
#pragma unroll
    for (int ks = 0; ks < 4; ++ks)
        qf[ks] = *(const bf16x8*)(Q + qkbase + (size_t)(q0 + l16) * LDQK + ks * 32 + lhi * 8);

    auto stageK = [&](int kt, int buf) {
#pragma unroll
        for (int j = 0; j < 2; ++j) {
            int idx = j * 512 + tid;
            int row = idx >> 4, c8 = idx & 15;
            int c8s = c8 ^ (row & 7);
            gld_lds16(K + qkbase + (size_t)(kt * 64 + row) * LDQK + c8s * 8,
                      &Ks[buf][0] + idx * 8);
        }
    };
    auto stageV = [&](int kt) {
#pragma unroll
        for (int j = 0; j < 2; ++j) {
            int idx = j * 512 + tid;
            int row = idx >> 3, c8 = idx & 7;
            int c8s = c8 ^ (row & 7);
            gld_lds16(Vt + vtbase + (size_t)row * SEQ + kt * 64 + c8s * 8, Vs + idx * 8);
        }
    };

    f32x4 accO[8] = {};
    float m_run[4], l_run[4];
#pragma unroll
    for (int r = 0; r < 4; ++r) { m_run[r] = -1e30f; l_run[r] = 0.f; }

    const float scale2 = 0.08838834764831845f * 1.4426950408889634f;
    const int NKT = (qt + 1) * 2;

    stageK(0, 0);
    VMCNT(0);
    BAR();
    SCHEDB();

    for (int kt = 0; kt < NKT; ++kt) {
        const int cb = kt & 1;
        const bool pf = (kt + 1 < NKT);
        stageV(kt);
        if (pf) stageK(kt + 1, cb ^ 1);

        f32x4 s[4] = {};
        __builtin_amdgcn_s_setprio(1);
#pragma unroll
        for (int nb = 0; nb < 4; ++nb) {
            const int tok = nb * 16 + l16;
#pragma unroll
            for (int ks = 0; ks < 4; ++ks) {
                int co = (ks * 64 + lhi * 16) ^ ((tok & 7) << 4);
                bf16x8 kf = *(const bf16x8*)((const char*)&Ks[cb][0] + tok * 256 + co);
                s[nb] = __builtin_amdgcn_mfma_f32_16x16x32_bf16(qf[ks], kf, s[nb], 0, 0, 0);
            }
        }
        __builtin_amdgcn_s_setprio(0);

        if (((kt + 1) << 6) > q0) {
#pragma unroll
            for (int nb = 0; nb < 4; ++nb)
#pragma unroll
                for (int r = 0; r < 4; ++r) {
                    float sv = s[nb][r] * scale2;
                    if ((kt * 64 + nb * 16 + l16) > (q0 + lhi * 4 + r)) sv = -1e30f;
                    s[nb][r] = sv;
                }
        } else {
#pragma unroll
            for (int nb = 0; nb < 4; ++nb)
#pragma unroll
                for (int r = 0; r < 4; ++r) s[nb][r] *= scale2;
        }

        float alpha[4];
#pragma unroll
        for (int r = 0; r < 4; ++r) {
            float mx = fmaxf(fmaxf(s[0][r], s[1][r]), fmaxf(s[2][r], s[3][r]));
#pragma unroll
            for (int m = 8; m; m >>= 1) mx = fmaxf(mx, __shfl_xor(mx, m, 64));
            float mnew = fmaxf(m_run[r], mx);
            alpha[r] = exp2f(m_run[r] - mnew);
            float rs = 0.f;
#pragma unroll
            for (int nb = 0; nb < 4; ++nb) {
                float p = exp2f(s[nb][r] - mnew);
                s[nb][r] = p;
                rs += p;
            }
#pragma unroll
            for (int m = 8; m; m >>= 1) rs += __shfl_xor(rs, m, 64);
            l_run[r] = l_run[r] * alpha[r] + rs;
            m_run[r] = mnew;
        }
#pragma unroll
        for (int d8 = 0; d8 < 8; ++d8)
#pragma unroll
            for (int r = 0; r < 4; ++r) accO[d8][r] *= alpha[r];
#pragma unroll
        for (int nb = 0; nb < 4; ++nb)
#pragma unroll
            for (int r = 0; r < 4; ++r)
                Pl[wid][(lhi * 4 + r) * 72 + nb * 16 + l16] = f2bf(s[nb][r]);

        if (pf) { VMCNT(2); } else { VMCNT(0); }
        BAR();
        SCHEDB();

        __builtin_amdgcn_s_setprio(1);
#pragma unroll
        for (int ks2 = 0; ks2 < 2; ++ks2) {
            bf16x8 pa = *(const bf16x8*)(&Pl[wid][l16 * 72 + ks2 * 32 + lhi * 8]);
#pragma unroll
            for (int d8 = 0; d8 < 8; ++d8) {
                const int d = d8 * 16 + l16;
                const int co = ((ks2 * 4 + lhi) ^ (d & 7)) << 4;
                bf16x8 vf = *(const bf16x8*)((const char*)Vs + d * 128 + co);
                accO[d8] = __builtin_amdgcn_mfma_f32_16x16x32_bf16(pa, vf, accO[d8], 0, 0, 0);
            }
        }
        __builtin_amdgcn_s_setprio(0);

        VMCNT(0);
        BAR();
        SCHEDB();
    }

#pragma unroll
    for (int d8 = 0; d8 < 8; ++d8)
#pragma unroll
        for (int r = 0; r < 4; ++r) {
            float o = accO[d8][r] / l_run[r];
            O[obase + (size_t)(q0 + lhi * 4 + r) * D_MODEL + d8 * 16 + l16] = f2bf(o);
        }
}

// ---------------- host launcher ----------------
extern "C" void kernel_launch(void* const* d_in, const int* in_sizes, int n_in,
                              void* d_out, int out_size, void* d_ws, size_t ws_size,
                              hipStream_t stream) {
    const float* x    = (const float*)d_in[0];
    const float* tok  = (const float*)d_in[1];
    const float* Wq   = (const float*)d_in[2];
    const float* Wk   = (const float*)d_in[3];
    const float* Wv   = (const float*)d_in[4];
    const float* Wo   = (const float*)d_in[5];
    const float* W1   = (const float*)d_in[6];
    const float* W2   = (const float*)d_in[7];
    const float* ln1w = (const float*)d_in[8];
    const float* ln1b = (const float*)d_in[9];
    const float* ln2w = (const float*)d_in[10];
    const float* ln2b = (const float*)d_in[11];
    float* out = (float*)d_out;

    char* ws = (char*)d_ws;
    size_t off = 0;
    auto alloc = [&](size_t bytes) { void* p = ws + off; off += bytes; return p; };
    __bf16* tokb  = (__bf16*)alloc((size_t)NTOK * D_MODEL * 2);       //   0-16 MB
    __bf16* hnorm = (__bf16*)alloc((size_t)NTOK * D_MODEL * 2);       //  16-32
    __bf16* wqb   = (__bf16*)alloc((size_t)D_MODEL * D_MODEL * 2);    //  32-40 (wq|wk adjacent)
    __bf16* wkb   = (__bf16*)alloc((size_t)D_MODEL * D_MODEL * 2);    //  40-48
    __bf16* wvb   = (__bf16*)alloc((size_t)D_MODEL * D_MODEL * 2);    //  48-56
    __bf16* wob   = (__bf16*)alloc((size_t)D_MODEL * D_MODEL * 2);    //  56-64
    __bf16* w1b   = (__bf16*)alloc((size_t)FF * D_MODEL * 2);         //  64-96
    __bf16* w2b   = (__bf16*)alloc((size_t)D_MODEL * FF * 2);         //  96-128
    __bf16* QKb   = (__bf16*)alloc((size_t)NTOK * 2 * D_MODEL * 2);   // 128-160
    __bf16* Vtg   = (__bf16*)alloc((size_t)NTOK * D_MODEL * 2);       // 160-176
    __bf16* Ab    = (__bf16*)alloc((size_t)NTOK * D_MODEL * 2);       // 176-192
    float*  x2    = (float*)alloc((size_t)NTOK * D_MODEL * 4);        // 192-224 f32
    __bf16* gb    = QKb;              // FFN intermediate aliases QKb.. (dead post O-proj)

    cvt_all<<<56 * 1024, 256, 0, stream>>>(tok, Wq, Wk, Wv, Wo, W1, W2,
                                           tokb, wqb, wkb, wvb, wob, w1b, w2b);

    ln_bf16<<<NTOK, 256, 0, stream>>>(x, ln1w, ln1b, hnorm);

    // grouped QK (256 tiles GEO0) + V (256 tiles GEO1) = 512 blocks, 2 full rounds
    gemm_qkv<<<512, 512, 0, stream>>>(hnorm, wqb, QKb, tokb, wvb, Vtg);

    attn_causal<<<dim3(SEQ / 128, NHEAD, BATCH), 512, 0, stream>>>(QKb, QKb + D_MODEL, Vtg, Ab);

    // O-proj: GEO1 (128x256) -> 256 blocks, full GPU; MAP=2 bm-stripes per XCD
    gemm_k<2, 1, 1, 2><<<256, 512, 0, stream>>>(Ab, wob, nullptr, x2, x,
                                                NTOK, D_MODEL, D_MODEL);

    ln_bf16<<<NTOK, 256, 0, stream>>>(x2, ln2w, ln2b, hnorm);

    // FFN1: GEO1 (128x256) -> 32x32 = 1024 blocks (4 full rounds)
    gemm_k<1, 1, 1, 0><<<1024, 512, 0, stream>>>(hnorm, w1b, gb, nullptr, nullptr,
                                                 NTOK, FF, D_MODEL);
    // W2: GEO1, K=8192 (128 tiles/block), 256 blocks, residual fused (no split-K,
    // no add_reduce, no 96 MB partial traffic)
    gemm_k<2, 1, 1, 0><<<256, 512, 0, stream>>>(gb, w2b, nullptr, out, x2,
                                                NTOK, D_MODEL, FF);
}

// Round 12
// 629.113 us; speedup vs baseline: 1.5640x; 1.0681x over previous
//
#include <hip/hip_runtime.h>
#include <hip/hip_bf16.h>
#include <math.h>

#define D_MODEL 2048
#define SEQ     2048
#define BATCH   2
#define NTOK    (BATCH*SEQ)      // 4096
#define NHEAD   16
#define HDIM    128
#define FF      8192

typedef float  f32x4  __attribute__((ext_vector_type(4)));
typedef __bf16 bf16x8 __attribute__((ext_vector_type(8)));

__device__ __forceinline__ unsigned short f2bfbits(float f) {
    unsigned u = __builtin_bit_cast(unsigned, f);
    return (unsigned short)((u + 0x7fffu + ((u >> 16) & 1u)) >> 16);
}
__device__ __forceinline__ __bf16 f2bf(float f) {
    unsigned short h = f2bfbits(f);
    return __builtin_bit_cast(__bf16, h);
}

__device__ __forceinline__ void gld_lds16(const void* g, void* l) {
    __builtin_amdgcn_global_load_lds(
        (const __attribute__((address_space(1))) unsigned int*)g,
        (__attribute__((address_space(3))) unsigned int*)l, 16, 0, 0);
}

#define BAR()      __builtin_amdgcn_s_barrier()
#define LGKM(N)    asm volatile("s_waitcnt lgkmcnt(" #N ")" ::: "memory")
#define VMCNT(N)   asm volatile("s_waitcnt vmcnt(" #N ")" ::: "memory")
#define SCHEDB()   __builtin_amdgcn_sched_barrier(0)

// ---------------- fused f32 -> bf16 convert for tok + all 6 weights -------------
__global__ __launch_bounds__(256) void cvt_all(
        const float* __restrict__ tok, const float* __restrict__ wq,
        const float* __restrict__ wk,  const float* __restrict__ wv,
        const float* __restrict__ wo,  const float* __restrict__ w1,
        const float* __restrict__ w2,
        __bf16* __restrict__ tokb, __bf16* __restrict__ wqb,
        __bf16* __restrict__ wkb,  __bf16* __restrict__ wvb,
        __bf16* __restrict__ wob,  __bf16* __restrict__ w1b,
        __bf16* __restrict__ w2b) {
    const size_t M4 = 4u * 1024 * 1024;
    size_t i = (size_t)blockIdx.x * 1024 + (size_t)threadIdx.x * 4;
    const float* src; __bf16* dst; size_t off;
    if      (i < 2*M4)  { src = tok; dst = tokb; off = i; }
    else if (i < 3*M4)  { src = wq;  dst = wqb;  off = i - 2*M4; }
    else if (i < 4*M4)  { src = wk;  dst = wkb;  off = i - 3*M4; }
    else if (i < 5*M4)  { src = wv;  dst = wvb;  off = i - 4*M4; }
    else if (i < 6*M4)  { src = wo;  dst = wob;  off = i - 5*M4; }
    else if (i < 10*M4) { src = w1;  dst = w1b;  off = i - 6*M4; }
    else                { src = w2;  dst = w2b;  off = i - 10*M4; }
    float4 v = *(const float4*)(src + off);
    ushort4 o;
    o.x = f2bfbits(v.x); o.y = f2bfbits(v.y);
    o.z = f2bfbits(v.z); o.w = f2bfbits(v.w);
    *(ushort4*)((unsigned short*)dst + off) = o;
}

// ---------------- split-K reduce: out = p0 + p1 + resid (f32) ----------------
__global__ __launch_bounds__(256) void add_reduce(
        const float* __restrict__ p0, const float* __restrict__ p1,
        const float* __restrict__ resid, float* __restrict__ out) {
    int i = blockIdx.x * 256 + threadIdx.x;
    float4 a = ((const float4*)p0)[i];
    float4 b = ((const float4*)p1)[i];
    float4 r = ((const float4*)resid)[i];
    float4 o;
    o.x = a.x + b.x + r.x; o.y = a.y + b.y + r.y;
    o.z = a.z + b.z + r.z; o.w = a.w + b.w + r.w;
    ((float4*)out)[i] = o;
}

// ---------------- LayerNorm: f32 in -> bf16 out, one block per row ----------------
__global__ __launch_bounds__(256) void ln_bf16(
        const float* __restrict__ x, const float* __restrict__ w,
        const float* __restrict__ b, __bf16* __restrict__ out) {
    const int row = blockIdx.x;
    const int tid = threadIdx.x;
    const float* xr = x + (size_t)row * D_MODEL;
    float4 v0 = *(const float4*)(xr + tid * 8);
    float4 v1 = *(const float4*)(xr + tid * 8 + 4);
    float va[8] = {v0.x, v0.y, v0.z, v0.w, v1.x, v1.y, v1.z, v1.w};
    float s = 0.f, ss = 0.f;
#pragma unroll
    for (int j = 0; j < 8; ++j) { s += va[j]; ss += va[j] * va[j]; }
#pragma unroll
    for (int m = 32; m; m >>= 1) { s += __shfl_xor(s, m, 64); ss += __shfl_xor(ss, m, 64); }
    __shared__ float red[8];
    const int wid = tid >> 6;
    if ((tid & 63) == 0) { red[wid * 2] = s; red[wid * 2 + 1] = ss; }
    __syncthreads();
    s  = red[0] + red[2] + red[4] + red[6];
    ss = red[1] + red[3] + red[5] + red[7];
    const float mu   = s * (1.0f / D_MODEL);
    const float var  = ss * (1.0f / D_MODEL) - mu * mu;
    const float rstd = rsqrtf(var + 1e-5f);
    const int c = tid * 8;
    ushort4 o0, o1;
    unsigned short ob[8];
#pragma unroll
    for (int j = 0; j < 8; ++j)
        ob[j] = f2bfbits((va[j] - mu) * rstd * w[c + j] + b[c + j]);
    o0.x = ob[0]; o0.y = ob[1]; o0.z = ob[2]; o0.w = ob[3];
    o1.x = ob[4]; o1.y = ob[5]; o1.z = ob[6]; o1.w = ob[7];
    ushort4* op = (ushort4*)(out + (size_t)row * D_MODEL + c);
    op[0] = o0; op[1] = o1;
}

// ================== GEMM core (device) ==================
// C[M,N] = A[M,K] @ B[N,K]^T, 512 threads = 8 waves.
// GEO=0: 256x256 tile, waves 2Mx4N own 128x64, acc[8][4]; 2 LDS buffers (128KB);
//        SINGLE-BARRIER K-tile: stage all of tile t+1 at tile-t top, issue all
//        24 ds_reads, all 64 MFMA — compiler schedules reads∥MFMA with its own
//        counted lgkmcnt (near-optimal per m97 asm analysis); waves free-run
//        within the tile (inter-wave LDS∥MFMA overlap). Hazards: within a tile
//        all waves only READ buf[cur]; staging targets buf[cur^1] whose last
//        readers (tile t-1) finished before the t-1→t barrier. One vmcnt(0) +
//        barrier per K-tile (staging issued a full tile earlier => latency hidden).
//        (R7/R9's 4-phase barriered variants measured ~790 TF, MfmaUtil 30% —
//        phase barriers serialized read-drain vs MFMA. R10's cross-phase reg
//        pipelining spilled to scratch. This removes the barriers instead.)
// GEO=1: 128x256 tile, waves own 64x64, acc[4][4]; 1 phase/K-tile, 3 buffers
//        (144KB), 2-tile-deep prefetch, counted vmcnt(6). For K=2048 N=2048
//        shapes only (V/O-proj): at FFN shapes its 128-row tile doubles B-panel
//        HBM traffic (R11: FETCH 532 MB, HBM-bound regression).
// Swizzle both-sides (rule #21): 16B-chunk col X ^= (r&7)<<4 -> 2-way = free.
// EPI: 0 bf16 | 1 GELU bf16 | 2 f32+resid | 3 bf16 transposed [b,h,hd,s] | 4 f32 partial

template <int EPI, int MM>
__device__ __forceinline__ void gemm_epi(
        f32x4 (*acc)[4], int BMsz, int WMsz,
        int bm, int bn, int wm, int wn, int lhi, int l16,
        int M, int N, int slice,
        __bf16* __restrict__ Cb, float* __restrict__ Cf,
        const float* __restrict__ resid) {
#pragma unroll
    for (int m = 0; m < MM; ++m) {
        const int row = bm * BMsz + wm * WMsz + m * 16 + lhi * 4;
#pragma unroll
        for (int n = 0; n < 4; ++n) {
            const int col = bn * 256 + wn * 64 + n * 16 + l16;
            if (EPI == 3) {
                const int h = col >> 7, hd = col & 127;
                const size_t obase =
                    ((((size_t)(row >> 11) * NHEAD + h) * HDIM + hd) << 11) + (row & 2047);
                ushort4 o;
                o.x = f2bfbits(acc[m][n][0]); o.y = f2bfbits(acc[m][n][1]);
                o.z = f2bfbits(acc[m][n][2]); o.w = f2bfbits(acc[m][n][3]);
                *(ushort4*)((unsigned short*)Cb + obase) = o;
            } else {
#pragma unroll
                for (int r = 0; r < 4; ++r) {
                    float v = acc[m][n][r];
                    size_t off = (size_t)(row + r) * N + col;
                    if (EPI == 0) {
                        Cb[off] = f2bf(v);
                    } else if (EPI == 1) {
                        Cb[off] = f2bf(0.5f * v * (1.0f + erff(v * 0.70710678118654752f)));
                    } else if (EPI == 2) {
                        Cf[off] = v + resid[off];
                    } else {  // EPI == 4: f32 partial per slice
                        Cf[(size_t)slice * M * N + off] = v;
                    }
                }
            }
        }
    }
}

template <int EPI, int SPLITK, int GEO>
__device__ __forceinline__ void gemm_core(
        const __bf16* __restrict__ A, const __bf16* __restrict__ Bm,
        __bf16* __restrict__ Cb, float* __restrict__ Cf,
        const float* __restrict__ resid, int M, int N, int K,
        int bm, int bn, int slice, char* smem) {
    const int tid = threadIdx.x;
    const int wid = tid >> 6, lane = tid & 63;
    const int l16 = lane & 15, lhi = lane >> 4;
    const int wm = wid >> 2, wn = wid & 3;
    const int tps = (K >> 6) / SPLITK;
    const int t0 = slice * tps, t1 = t0 + tps;

    // stage 128 rows x 64 cols (16KB): inverse-swizzled source, linear LDS dest
    auto stage128 = [&](char* dst, const __bf16* G, int kt, int rowOff) {
#pragma unroll
        for (int j = 0; j < 2; ++j) {
            int idx = j * 512 + tid;            // 0..1023 chunks
            int r = idx >> 3;                   // 0..127
            int Xc = (idx & 7) << 4;
            int Xs = Xc ^ ((r & 7) << 4);
            gld_lds16((const char*)(G + ((size_t)(rowOff + r) * K + kt * 64)) + Xs,
                      dst + idx * 16);
        }
    };

    if constexpr (GEO == 0) {
        const __bf16* Ag = A  + (size_t)bm * 256 * K;
        const __bf16* Bg = Bm + (size_t)bn * 256 * K;
        f32x4 acc[8][4] = {};
        bf16x8 af0[4][2], af1[4][2], bq0[2][2], bq1[2][2];
        const char *Ab_, *Bb_;
        auto ldA = [&](bf16x8 (&dst)[4][2], int qm) {
#pragma unroll
            for (int i = 0; i < 4; ++i)
#pragma unroll
                for (int ks = 0; ks < 2; ++ks) {
                    int r = wm * 128 + (qm * 4 + i) * 16 + l16;
                    int X = ks * 64 + lhi * 16;
                    dst[i][ks] = *(const bf16x8*)(Ab_ + r * 128 + (X ^ ((r & 7) << 4)));
                }
        };
        auto ldB = [&](bf16x8 (&dst)[2][2], int qn) {
#pragma unroll
            for (int j = 0; j < 2; ++j)
#pragma unroll
                for (int ks = 0; ks < 2; ++ks) {
                    int r = wn * 64 + (qn * 2 + j) * 16 + l16;
                    int X = ks * 64 + lhi * 16;
                    dst[j][ks] = *(const bf16x8*)(Bb_ + r * 128 + (X ^ ((r & 7) << 4)));
                }
        };
        auto mfmaQ = [&](bf16x8 (&a)[4][2], bf16x8 (&b)[2][2], int mo, int no) {
#pragma unroll
            for (int i = 0; i < 4; ++i)
#pragma unroll
                for (int j = 0; j < 2; ++j)
#pragma unroll
                    for (int ks = 0; ks < 2; ++ks)
                        acc[mo + i][no + j] = __builtin_amdgcn_mfma_f32_16x16x32_bf16(
                            a[i][ks], b[j][ks], acc[mo + i][no + j], 0, 0, 0);
        };
        auto stageT = [&](int t, int c) {
            char* base = smem + c * 65536;
            stage128(base,         Ag, t, 0);
            stage128(base + 16384, Ag, t, 128);
            stage128(base + 32768, Bg, t, 0);
            stage128(base + 49152, Bg, t, 128);
        };

        stageT(t0, 0);
        VMCNT(0);
        BAR();

        for (int t = t0; t < t1; ++t) {
            const int cur = (t - t0) & 1;
            Ab_ = smem + cur * 65536;
            Bb_ = Ab_ + 32768;
            const bool pf = (t + 1 < t1);
            // single-barrier K-tile: stage t+1, read everything, compute everything;
            // compiler interleaves ds_reads with MFMAs via counted lgkmcnt, waves
            // free-run (no intra-tile barriers needed — see hazard proof above)
            if (pf) stageT(t + 1, cur ^ 1);
            ldA(af0, 0); ldB(bq0, 0);
            __builtin_amdgcn_s_setprio(1);
            mfmaQ(af0, bq0, 0, 0);
            ldB(bq1, 1);
            mfmaQ(af0, bq1, 0, 2);
            ldA(af1, 1);
            mfmaQ(af1, bq0, 4, 0);
            mfmaQ(af1, bq1, 4, 2);
            __builtin_amdgcn_s_setprio(0);
            if (pf) VMCNT(0);   // t+1 staging landed (issued a full tile ago)
            BAR();
        }
        gemm_epi<EPI, 8>(acc, 256, 128, bm, bn, wm, wn, lhi, l16,
                         M, N, slice, Cb, Cf, resid);
    } else {
        // GEO1: 128x256 tile, 3 buffers (48KB each), 2-tile-deep, counted vmcnt(6)
        const __bf16* Ag = A  + (size_t)bm * 128 * K;
        const __bf16* Bg = Bm + (size_t)bn * 256 * K;
        f32x4 acc[4][4] = {};
        auto stageT = [&](int t, int c) {
            char* base = smem + c * 49152;
            stage128(base,         Ag, t, 0);      // A: 128x64 = 16KB
            stage128(base + 16384, Bg, t, 0);      // B: 256x64 = 32KB
            stage128(base + 32768, Bg, t, 128);
        };
        stageT(t0, 0);
        if (t0 + 1 < t1) {
            stageT(t0 + 1, 1);
            VMCNT(6);
        } else {
            VMCNT(0);
        }
        BAR();

        for (int t = t0; t < t1; ++t) {
            const int c = (t - t0) % 3;
            if (t + 2 < t1) stageT(t + 2, (c + 2) % 3);   // buf died at t-1's end barrier
            const char* Ab_ = smem + c * 49152;
            const char* Bb_ = Ab_ + 16384;
            bf16x8 af[4][2], bq[4][2];
#pragma unroll
            for (int i = 0; i < 4; ++i)
#pragma unroll
                for (int ks = 0; ks < 2; ++ks) {
                    int r = wm * 64 + i * 16 + l16;
                    int X = ks * 64 + lhi * 16;
                    af[i][ks] = *(const bf16x8*)(Ab_ + r * 128 + (X ^ ((r & 7) << 4)));
                }
#pragma unroll
            for (int j = 0; j < 4; ++j)
#pragma unroll
                for (int ks = 0; ks < 2; ++ks) {
                    int r = wn * 64 + j * 16 + l16;
                    int X = ks * 64 + lhi * 16;
                    bq[j][ks] = *(const bf16x8*)(Bb_ + r * 128 + (X ^ ((r & 7) << 4)));
                }
            __builtin_amdgcn_s_setprio(1);
#pragma unroll
            for (int i = 0; i < 4; ++i)
#pragma unroll
                for (int j = 0; j < 4; ++j)
#pragma unroll
                    for (int ks = 0; ks < 2; ++ks)
                        acc[i][j] = __builtin_amdgcn_mfma_f32_16x16x32_bf16(
                            af[i][ks], bq[j][ks], acc[i][j], 0, 0, 0);
            __builtin_amdgcn_s_setprio(0);
            // gate t+1's buffer: counted vmcnt BEFORE barrier
            if (t + 2 < t1) {
                VMCNT(6);
                BAR();
            } else if (t + 1 < t1) {
                VMCNT(0);
                BAR();
            }
        }
        gemm_epi<EPI, 4>(acc, 128, 64, bm, bn, wm, wn, lhi, l16,
                         M, N, slice, Cb, Cf, resid);
    }
}

// MAP: 0 = generic XCD round-robin swizzle; 1 = bn-stripes of 4 per XCD (FFN1:
// A-panel + 4MB B resident per XCD); 2 = bm-stripes of 4 per XCD (O-proj).
template <int EPI, int SPLITK, int GEO, int MAP>
__global__ __launch_bounds__(512, 2) void gemm_k(
        const __bf16* __restrict__ A, const __bf16* __restrict__ Bm,
        __bf16* __restrict__ Cb, float* __restrict__ Cf,
        const float* __restrict__ resid, int M, int N, int K) {
    __shared__ __align__(16) char smem[GEO ? 147456 : 131072];
    int bm, bn, slice = 0;
    if (MAP == 0) {
        int id = blockIdx.x;
        const int cpx = gridDim.x >> 3;
        id = (id & 7) * cpx + (id >> 3);
        const int nbn = N >> 8;
        if (SPLITK == 2) {
            const int nblk = (M >> (GEO ? 7 : 8)) * nbn;
            slice = id / nblk;
            id -= slice * nblk;
        }
        bm = id / nbn; bn = id % nbn;
    } else if (MAP == 1) {
        const int x = blockIdx.x & 7, j = blockIdx.x >> 3;
        bn = (x << 2) | (j & 3); bm = j >> 2;
    } else {
        const int x = blockIdx.x & 7, j = blockIdx.x >> 3;
        bm = (x << 2) | (j & 3); bn = j >> 2;
    }
    gemm_core<EPI, SPLITK, GEO>(A, Bm, Cb, Cf, resid, M, N, K, bm, bn, slice, smem);
}

// Grouped QK + V projection: 512 blocks. Per XCD x: j<32 -> QK tile (256x256),
// j>=32 -> V tile (128x256, EPI=3 transposed out).
__global__ __launch_bounds__(512, 2) void gemm_qkv(
        const __bf16* __restrict__ hn, const __bf16* __restrict__ wqk,
        __bf16* __restrict__ QKb, const __bf16* __restrict__ tokb,
        const __bf16* __restrict__ wv, __bf16* __restrict__ Vtg) {
    __shared__ __align__(16) char smem[147456];
    const int x = blockIdx.x & 7, j = blockIdx.x >> 3;   // x = XCD, j = 0..63
    if (j < 32) {
        const int bm = ((x >> 1) << 2) | (j & 3);        // 0..15
        const int bn = ((x & 1) << 3) | (j >> 2);        // 0..15
        gemm_core<0, 1, 0>(hn, wqk, QKb, nullptr, nullptr,
                           NTOK, 2 * D_MODEL, D_MODEL, bm, bn, 0, smem);
    } else {
        const int jv = j - 32;
        const int bm = ((x >> 1) << 3) | (jv & 7);       // 0..31
        const int bn = ((x & 1) << 2) | (jv >> 3);       // 0..7
        gemm_core<3, 1, 1>(tokb, wv, Vtg, nullptr, nullptr,
                           NTOK, D_MODEL, D_MODEL, bm, bn, 0, smem);
    }
}

// ---------------- Causal flash attention (8 waves, QBLK=128, pipelined) ----------
#define LDQK 4096
__global__ __launch_bounds__(512) void attn_causal(
        const __bf16* __restrict__ Q, const __bf16* __restrict__ K,
        const __bf16* __restrict__ Vt, __bf16* __restrict__ O) {
    const int qt = gridDim.x - 1 - blockIdx.x;
    const int h = blockIdx.y, bb = blockIdx.z;
    const int tid = threadIdx.x, wid = tid >> 6, lane = tid & 63;
    const int l16 = lane & 15, lhi = lane >> 4;
    __shared__ __align__(16) __bf16 Ks[2][64 * 128];
    __shared__ __align__(16) __bf16 Vs[128 * 64];
    __shared__ __align__(16) __bf16 Pl[8][16 * 72];

    const size_t qkbase = ((size_t)bb * SEQ) * LDQK + (size_t)h * HDIM;
    const size_t obase  = ((size_t)bb * SEQ) * D_MODEL + (size_t)h * HDIM;
    const size_t vtbase = (((size_t)bb * NHEAD + h) * HDIM) << 11;
    const int q0 = qt * 128 + wid * 16;

    bf16x8 qf[4];
#pragma unroll
    for (int ks = 0; ks < 4; ++ks)
        qf[ks] = *(const bf16x8*)(Q + qkbase + (size_t)(q0 + l16) * LDQK + ks * 32 + lhi * 8);

    auto stageK = [&](int kt, int buf) {
#pragma unroll
        for (int j = 0; j < 2; ++j) {
            int idx = j * 512 + tid;
            int row = idx >> 4, c8 = idx & 15;
            int c8s = c8 ^ (row & 7);
            gld_lds16(K + qkbase + (size_t)(kt * 64 + row) * LDQK + c8s * 8,
                      &Ks[buf][0] + idx * 8);
        }
    };
    auto stageV = [&](int kt) {
#pragma unroll
        for (int j = 0; j < 2; ++j) {
            int idx = j * 512 + tid;
            int row = idx >> 3, c8 = idx & 7;
            int c8s = c8 ^ (row & 7);
            gld_lds16(Vt + vtbase + (size_t)row * SEQ + kt * 64 + c8s * 8, Vs + idx * 8);
        }
    };

    f32x4 accO[8] = {};
    float m_run[4], l_run[4];
#pragma unroll
    for (int r = 0; r < 4; ++r) { m_run[r] = -1e30f; l_run[r] = 0.f; }

    const float scale2 = 0.08838834764831845f * 1.4426950408889634f;
    const int NKT = (qt + 1) * 2;

    stageK(0, 0);
    VMCNT(0);
    BAR();
    SCHEDB();

    for (int kt = 0; kt < NKT; ++kt) {
        const int cb = kt & 1;
        const bool pf = (kt + 1 < NKT);
        stageV(kt);
        if (pf) stageK(kt + 1, cb ^ 1);

        f32x4 s[4] = {};
        __builtin_amdgcn_s_setprio(1);
#pragma unroll
        for (int nb = 0; nb < 4; ++nb) {
            const int tok = nb * 16 + l16;
#pragma unroll
            for (int ks = 0; ks < 4; ++ks) {
                int co = (ks * 64 + lhi * 16) ^ ((tok & 7) << 4);
                bf16x8 kf = *(const bf16x8*)((const char*)&Ks[cb][0] + tok * 256 + co);
                s[nb] = __builtin_amdgcn_mfma_f32_16x16x32_bf16(qf[ks], kf, s[nb], 0, 0, 0);
            }
        }
        __builtin_amdgcn_s_setprio(0);

        if (((kt + 1) << 6) > q0) {
#pragma unroll
            for (int nb = 0; nb < 4; ++nb)
#pragma unroll
                for (int r = 0; r < 4; ++r) {
                    float sv = s[nb][r] * scale2;
                    if ((kt * 64 + nb * 16 + l16) > (q0 + lhi * 4 + r)) sv = -1e30f;
                    s[nb][r] = sv;
                }
        } else {
#pragma unroll
            for (int nb = 0; nb < 4; ++nb)
#pragma unroll
                for (int r = 0; r < 4; ++r) s[nb][r] *= scale2;
        }

        float alpha[4];
#pragma unroll
        for (int r = 0; r < 4; ++r) {
            float mx = fmaxf(fmaxf(s[0][r], s[1][r]), fmaxf(s[2][r], s[3][r]));
#pragma unroll
            for (int m = 8; m; m >>= 1) mx = fmaxf(mx, __shfl_xor(mx, m, 64));
            float mnew = fmaxf(m_run[r], mx);
            alpha[r] = exp2f(m_run[r] - mnew);
            float rs = 0.f;
#pragma unroll
            for (int nb = 0; nb < 4; ++nb) {
                float p = exp2f(s[nb][r] - mnew);
                s[nb][r] = p;
                rs += p;
            }
#pragma unroll
            for (int m = 8; m; m >>= 1) rs += __shfl_xor(rs, m, 64);
            l_run[r] = l_run[r] * alpha[r] + rs;
            m_run[r] = mnew;
        }
#pragma unroll
        for (int d8 = 0; d8 < 8; ++d8)
#pragma unroll
            for (int r = 0; r < 4; ++r) accO[d8][r] *= alpha[r];
#pragma unroll
        for (int nb = 0; nb < 4; ++nb)
#pragma unroll
            for (int r = 0; r < 4; ++r)
                Pl[wid][(lhi * 4 + r) * 72 + nb * 16 + l16] = f2bf(s[nb][r]);

        if (pf) { VMCNT(2); } else { VMCNT(0); }
        BAR();
        SCHEDB();

        __builtin_amdgcn_s_setprio(1);
#pragma unroll
        for (int ks2 = 0; ks2 < 2; ++ks2) {
            bf16x8 pa = *(const bf16x8*)(&Pl[wid][l16 * 72 + ks2 * 32 + lhi * 8]);
#pragma unroll
            for (int d8 = 0; d8 < 8; ++d8) {
                const int d = d8 * 16 + l16;
                const int co = ((ks2 * 4 + lhi) ^ (d & 7)) << 4;
                bf16x8 vf = *(const bf16x8*)((const char*)Vs + d * 128 + co);
                accO[d8] = __builtin_amdgcn_mfma_f32_16x16x32_bf16(pa, vf, accO[d8], 0, 0, 0);
            }
        }
        __builtin_amdgcn_s_setprio(0);

        VMCNT(0);
        BAR();
        SCHEDB();
    }

#pragma unroll
    for (int d8 = 0; d8 < 8; ++d8)
#pragma unroll
        for (int r = 0; r < 4; ++r) {
            float o = accO[d8][r] / l_run[r];
            O[obase + (size_t)(q0 + lhi * 4 + r) * D_MODEL + d8 * 16 + l16] = f2bf(o);
        }
}

// ---------------- host launcher ----------------
extern "C" void kernel_launch(void* const* d_in, const int* in_sizes, int n_in,
                              void* d_out, int out_size, void* d_ws, size_t ws_size,
                              hipStream_t stream) {
    const float* x    = (const float*)d_in[0];
    const float* tok  = (const float*)d_in[1];
    const float* Wq   = (const float*)d_in[2];
    const float* Wk   = (const float*)d_in[3];
    const float* Wv   = (const float*)d_in[4];
    const float* Wo   = (const float*)d_in[5];
    const float* W1   = (const float*)d_in[6];
    const float* W2   = (const float*)d_in[7];
    const float* ln1w = (const float*)d_in[8];
    const float* ln1b = (const float*)d_in[9];
    const float* ln2w = (const float*)d_in[10];
    const float* ln2b = (const float*)d_in[11];
    float* out = (float*)d_out;

    char* ws = (char*)d_ws;
    size_t off = 0;
    auto alloc = [&](size_t bytes) { void* p = ws + off; off += bytes; return p; };
    __bf16* tokb  = (__bf16*)alloc((size_t)NTOK * D_MODEL * 2);       //   0-16 MB
    __bf16* hnorm = (__bf16*)alloc((size_t)NTOK * D_MODEL * 2);       //  16-32
    __bf16* wqb   = (__bf16*)alloc((size_t)D_MODEL * D_MODEL * 2);    //  32-40 (wq|wk adjacent)
    __bf16* wkb   = (__bf16*)alloc((size_t)D_MODEL * D_MODEL * 2);    //  40-48
    __bf16* wvb   = (__bf16*)alloc((size_t)D_MODEL * D_MODEL * 2);    //  48-56
    __bf16* wob   = (__bf16*)alloc((size_t)D_MODEL * D_MODEL * 2);    //  56-64
    __bf16* w1b   = (__bf16*)alloc((size_t)FF * D_MODEL * 2);         //  64-96
    __bf16* w2b   = (__bf16*)alloc((size_t)D_MODEL * FF * 2);         //  96-128
    __bf16* QKb   = (__bf16*)alloc((size_t)NTOK * 2 * D_MODEL * 2);   // 128-160
    __bf16* Vtg   = (__bf16*)alloc((size_t)NTOK * D_MODEL * 2);       // 160-176
    __bf16* Ab    = (__bf16*)alloc((size_t)NTOK * D_MODEL * 2);       // 176-192
    float*  x2    = (float*)alloc((size_t)NTOK * D_MODEL * 4);        // 192-224 f32
    __bf16* gb    = QKb;              // FFN intermediate aliases QKb.. (dead post O-proj)
    float*  p0    = (float*)(ws);     // W2 split-K partials: 0-32MB / 32-64MB
    float*  p1    = p0 + (size_t)NTOK * D_MODEL;

    cvt_all<<<56 * 1024, 256, 0, stream>>>(tok, Wq, Wk, Wv, Wo, W1, W2,
                                           tokb, wqb, wkb, wvb, wob, w1b, w2b);

    ln_bf16<<<NTOK, 256, 0, stream>>>(x, ln1w, ln1b, hnorm);

    // grouped QK (256 tiles GEO0) + V (256 tiles GEO1) = 512 blocks, 2 full rounds
    gemm_qkv<<<512, 512, 0, stream>>>(hnorm, wqb, QKb, tokb, wvb, Vtg);

    attn_causal<<<dim3(SEQ / 128, NHEAD, BATCH), 512, 0, stream>>>(QKb, QKb + D_MODEL, Vtg, Ab);

    // O-proj: GEO1 (128x256) -> 256 blocks, full GPU; MAP=2 bm-stripes per XCD
    gemm_k<2, 1, 1, 2><<<256, 512, 0, stream>>>(Ab, wob, nullptr, x2, x,
                                                NTOK, D_MODEL, D_MODEL);

    ln_bf16<<<NTOK, 256, 0, stream>>>(x2, ln2w, ln2b, hnorm);

    // FFN1: GEO0 MAP=1 bn-stripes of 4 per XCD (A-panel resident, B 4MB resident)
    gemm_k<1, 1, 0, 1><<<512, 512, 0, stream>>>(hnorm, w1b, gb, nullptr, nullptr,
                                                NTOK, FF, D_MODEL);
    // W2: GEO0 split-K=2 (256 blocks), f32 partials + fused reduce+residual
    gemm_k<4, 2, 0, 0><<<256, 512, 0, stream>>>(gb, w2b, nullptr, p0, nullptr,
                                                NTOK, D_MODEL, FF);
    add_reduce<<<(NTOK * D_MODEL) / 1024, 256, 0, stream>>>(p0, p1, x2, out);
}